// Round 5
// baseline (878.007 us; speedup 1.0000x reference)
//
#include <hip/hip_runtime.h>
#include <stdint.h>

// Problem dims
#define NB  256
#define NT  100
#define NIN 128
#define NH  1024
#define NOUT 35

// d_out float offsets
#define O_SPK2 26214400ull
#define O_SPK3 52428800ull
#define O_SPK4 78643200ull
#define O_MEM4 79539200ull

// d_ws byte offsets
#define WS_XT   0ull          // 25600*128*4 = 13107200 (x/15, [t*256+b][i])
#define WS_Q1T  13107200ull   // 128*1024*4  = 524288 (q1X interleaved [i][tid][n])
#define WS_K2T  13631488ull   // 1048576
#define WS_K3T  14680064ull   // 1048576
#define WS_K4T  15728640ull   // 1024*48 = 49152 (padded stride 48)

// scale = (w_max - w_min)/15 computed in python fp64 then cast to fp32
#define S2C ((float)((1.0 - 0.001) / 15.0))
#define S1C ((float)(1.0 / 15.0))

// LDS-only barrier: no vmcnt drain (all inter-wave state in k_main is LDS)
#define BARRIER() do { \
  asm volatile("s_waitcnt lgkmcnt(0)" ::: "memory"); \
  __builtin_amdgcn_s_barrier(); \
  asm volatile("" ::: "memory"); \
} while (0)

// ------------------------------------------------------------------
// K1: quantize weights. w2/w3 via LDS-tiled transpose; k4T; q1X
// (interleaved [i][tid][n] so k_spk1 loads q as dwordx4); xt = x/15.
// ------------------------------------------------------------------
__global__ __launch_bounds__(256) void k_prep(const float* __restrict__ x,
                       const float* __restrict__ w1,
                       const float* __restrict__ w2, const float* __restrict__ w3,
                       const float* __restrict__ w4, uint8_t* __restrict__ ws)
{
  const int bid = blockIdx.x, tid = threadIdx.x;
  if (bid < 512) {                          // 64x64 tile transpose-quantize
    const float* W = (bid < 256) ? w2 : w3;
    uint8_t* K = ws + ((bid < 256) ? WS_K2T : WS_K3T);
    const int tb = bid & 255;
    const int i0 = (tb & 15) << 6, j0 = (tb >> 4) << 6;
    __shared__ uint8_t tile[64 * 68];       // [i_local][j_local], stride 68
    const int jl = tid >> 4, iq = (tid & 15) << 2;
    #pragma unroll
    for (int k = 0; k < 4; ++k) {
      const int jloc = jl + k * 16;
      const float4 v = *(const float4*)&W[(size_t)(j0 + jloc) * 1024 + i0 + iq];
      float wc;
      wc = fminf(fmaxf(v.x, 0.001f), 1.0f); tile[(iq + 0) * 68 + jloc] = (uint8_t)(int)rintf((wc - 0.001f) / S2C);
      wc = fminf(fmaxf(v.y, 0.001f), 1.0f); tile[(iq + 1) * 68 + jloc] = (uint8_t)(int)rintf((wc - 0.001f) / S2C);
      wc = fminf(fmaxf(v.z, 0.001f), 1.0f); tile[(iq + 2) * 68 + jloc] = (uint8_t)(int)rintf((wc - 0.001f) / S2C);
      wc = fminf(fmaxf(v.w, 0.001f), 1.0f); tile[(iq + 3) * 68 + jloc] = (uint8_t)(int)rintf((wc - 0.001f) / S2C);
    }
    __syncthreads();
    const int li = tid >> 2, cq = tid & 3;
    const uint32_t* tp = (const uint32_t*)&tile[li * 68 + (cq << 4)];
    *(uint4*)&K[(size_t)(i0 + li) * 1024 + j0 + (cq << 4)] =
        make_uint4(tp[0], tp[1], tp[2], tp[3]);
    return;
  }
  long long id = (long long)(bid - 512) * 256 + tid;
  if (id < 49152) {                         // k4T stride 48, pad j>=35 with 0
    int i = (int)(id / 48), j = (int)(id % 48);
    uint8_t v = 0;
    if (j < NOUT) {
      float wv = w4[(size_t)j * 1024 + i];
      float wc = fminf(fmaxf(wv, 0.001f), 1.0f);
      v = (uint8_t)(int)rintf((wc - 0.001f) / S2C);
    }
    ws[WS_K4T + id] = v;
    return;
  }
  id -= 49152;
  if (id < 131072) {                        // q1X[i][j&255][j>>8] = fake_quant(w1[j][i])
    int i = (int)(id >> 10), j = (int)(id & 1023);
    float wv = w1[(size_t)j * 128 + i];
    float wc = fminf(fmaxf(wv, -0.5f), 0.5f);
    float q = rintf((wc + 0.5f) / S1C) * S1C - 0.5f;
    ((float*)(ws + WS_Q1T))[(size_t)i * 1024 + ((j & 255) << 2) + (j >> 8)] = q;
    return;
  }
  id -= 131072;
  if (id < 3276800) {                       // xt[(t*256+b)*128+i] = x[b][t][i]/15
    int row = (int)(id >> 7), i = (int)(id & 127);
    int tt = row >> 8, bb = row & 255;
    ((float*)(ws + WS_XT))[id] = x[((size_t)bb * NT + tt) * NIN + i] / 15.0f;
  }
}

// ------------------------------------------------------------------
// K2 (v5): fused layer-1 GEMM + LIF scan. 256 threads x 4 neurons
// (tid, +256, +512, +768 via interleaved q1X float4). x rows are
// wave-uniform constant-index loads from the pre-divided xt table
// (scalarizable to s_load). FMA chain ascending-i per (t,j) --
// bitwise identical to prior passing versions.
// ------------------------------------------------------------------
__global__ __launch_bounds__(256, 1) void k_spk1(const float* __restrict__ xt,
                                                 const float* __restrict__ q1X,
                                                 float* __restrict__ out)
{
  const int b = blockIdx.x;
  const int tid = threadIdx.x;              // 0..255
  float m[4] = {0.f, 0.f, 0.f, 0.f};

  for (int c = 0; c < 4; ++c) {
    float acc[4][25];
    #pragma unroll
    for (int tt = 0; tt < 25; ++tt) {
      acc[0][tt] = 0.f; acc[1][tt] = 0.f; acc[2][tt] = 0.f; acc[3][tt] = 0.f;
    }
    for (int ib = 0; ib < 16; ++ib) {       // 8 i per ib, rolled (small I$)
      float4 q[8];                          // q[u] = {q(i, tid), q(i, tid+256), ...}
      #pragma unroll
      for (int u = 0; u < 8; ++u)
        q[u] = *(const float4*)&q1X[(size_t)(ib * 8 + u) * 1024 + (tid << 2)];
      #pragma unroll
      for (int tt = 0; tt < 25; ++tt) {
        const float* xr = xt + ((size_t)(c * 25 + tt) * NB + b) * NIN + ib * 8;
        const float4 xa = *(const float4*)xr;
        const float4 xc = *(const float4*)(xr + 4);
        float xs[8] = {xa.x, xa.y, xa.z, xa.w, xc.x, xc.y, xc.z, xc.w};
        #pragma unroll
        for (int u = 0; u < 8; ++u) {
          acc[0][tt] = fmaf(xs[u], q[u].x, acc[0][tt]);
          acc[1][tt] = fmaf(xs[u], q[u].y, acc[1][tt]);
          acc[2][tt] = fmaf(xs[u], q[u].z, acc[2][tt]);
          acc[3][tt] = fmaf(xs[u], q[u].w, acc[3][tt]);
        }
      }
    }
    // sequential LIF scan (subtract-reset), identical math/order
    #pragma unroll
    for (int tt = 0; tt < 25; ++tt) {
      const int t = c * 25 + tt;
      const size_t row = ((size_t)t * NB + b) * (size_t)NH;
      #pragma unroll
      for (int n = 0; n < 4; ++n) {
        float rst = m[n] > 1.0f ? 1.0f : 0.0f;
        m[n] = fmaf(0.9f, m[n], acc[n][tt]) - rst;
        out[row + n * 256 + tid] = ((m[n] - 1.0f) > 0.0f) ? 1.0f : 0.0f;
      }
    }
  }
}

// ------------------------------------------------------------------
// K3: persistent per-batch-element SNN loop, 1024 threads.
// depth-4 gather pipelining, atomic-free list build, packed-u16 gsum,
// fused rowsums, and lgkmcnt-only barriers (no vmcnt drain).
// ------------------------------------------------------------------
#define ACC(V) do { \
  aE0 += (V).x & 0x00FF00FFu; aO0 += ((V).x >> 8) & 0x00FF00FFu; \
  aE1 += (V).y & 0x00FF00FFu; aO1 += ((V).y >> 8) & 0x00FF00FFu; \
  aE2 += (V).z & 0x00FF00FFu; aO2 += ((V).z >> 8) & 0x00FF00FFu; \
  aE3 += (V).w & 0x00FF00FFu; aO3 += ((V).w >> 8) & 0x00FF00FFu; } while (0)

__global__ __launch_bounds__(1024, 1) void k_main(
    const uint8_t* __restrict__ k2T, const uint8_t* __restrict__ k3T,
    const uint8_t* __restrict__ k4T, float* __restrict__ out)
{
  const int b = blockIdx.x;
  const int tid = threadIdx.x;
  const int lane = tid & 63;
  const int wave = tid >> 6;                // 16 gather groups

  __shared__ uint16_t list[1024];
  __shared__ uint4    pEa4[1024];           // [g][lane*4..+3] packed u16 (neurons 0,2 of quad)
  __shared__ uint4    pOa4[1024];           // neurons 1,3
  __shared__ uint4    wcnt4[4];
  uint32_t* pEa  = (uint32_t*)pEa4;
  uint32_t* pOa  = (uint32_t*)pOa4;
  uint32_t* wcnt = (uint32_t*)wcnt4;

  float m2 = 0.f, m3 = 0.f, m4 = 0.f;
  uint32_t nT, nL; bool cm;

  auto buildList = [&](uint64_t bal) {      // after barrier A (wcnt populated)
    const uint4 c0 = wcnt4[0], c1 = wcnt4[1], c2 = wcnt4[2], c3 = wcnt4[3];
    nT = c0.x + c0.y + c0.z + c0.w + c1.x + c1.y + c1.z + c1.w +
         c2.x + c2.y + c2.z + c2.w + c3.x + c3.y + c3.z + c3.w;
    cm = nT > 512;
    nL = cm ? (1024u - nT) : nT;
    uint32_t pre = 0;
    const int w = wave;
    pre += (w > 0)  ? c0.x : 0u;  pre += (w > 1)  ? c0.y : 0u;
    pre += (w > 2)  ? c0.z : 0u;  pre += (w > 3)  ? c0.w : 0u;
    pre += (w > 4)  ? c1.x : 0u;  pre += (w > 5)  ? c1.y : 0u;
    pre += (w > 6)  ? c1.z : 0u;  pre += (w > 7)  ? c1.w : 0u;
    pre += (w > 8)  ? c2.x : 0u;  pre += (w > 9)  ? c2.y : 0u;
    pre += (w > 10) ? c2.z : 0u;  pre += (w > 11) ? c2.w : 0u;
    pre += (w > 12) ? c3.x : 0u;  pre += (w > 13) ? c3.y : 0u;
    pre += (w > 14) ? c3.z : 0u;
    const uint32_t bs = cm ? ((uint32_t)(w << 6) - pre) : pre;
    const uint64_t cw = cm ? ~bal : bal;
    if ((cw >> lane) & 1ull)
      list[bs + (uint32_t)__popcll(cw & ((1ull << lane) - 1ull))] = (uint16_t)tid;
  };

  auto gatherBig = [&](const uint8_t* __restrict__ mat, uint32_t nLv) {
    uint32_t aE0=0,aE1=0,aE2=0,aE3=0,aO0=0,aO1=0,aO2=0,aO3=0;
    const uint8_t* bp = mat + (lane << 4);  // 64 lanes x 16B = full 1KB row
    uint32_t a = (uint32_t)wave;
    for (; a + 48 < nLv; a += 64) {         // 4 loads in flight
      uint32_t i0 = (uint32_t)__builtin_amdgcn_readfirstlane((int)list[a]);
      uint32_t i1 = (uint32_t)__builtin_amdgcn_readfirstlane((int)list[a + 16]);
      uint32_t i2 = (uint32_t)__builtin_amdgcn_readfirstlane((int)list[a + 32]);
      uint32_t i3 = (uint32_t)__builtin_amdgcn_readfirstlane((int)list[a + 48]);
      const uint4 v0 = *(const uint4*)(bp + ((size_t)i0 << 10));
      const uint4 v1 = *(const uint4*)(bp + ((size_t)i1 << 10));
      const uint4 v2 = *(const uint4*)(bp + ((size_t)i2 << 10));
      const uint4 v3 = *(const uint4*)(bp + ((size_t)i3 << 10));
      ACC(v0); ACC(v1); ACC(v2); ACC(v3);
    }
    for (; a < nLv; a += 16) {
      uint32_t i0 = (uint32_t)__builtin_amdgcn_readfirstlane((int)list[a]);
      const uint4 v0 = *(const uint4*)(bp + ((size_t)i0 << 10));
      ACC(v0);
    }
    const int basei = (wave << 8) + (lane << 2);
    *(uint4*)&pEa[basei] = make_uint4(aE0, aE1, aE2, aE3);
    *(uint4*)&pOa[basei] = make_uint4(aO0, aO1, aO2, aO3);
  };

  auto gatherAll = [&](const uint8_t* __restrict__ mat) {   // all 1024 rows
    uint32_t aE0=0,aE1=0,aE2=0,aE3=0,aO0=0,aO1=0,aO2=0,aO3=0;
    const uint8_t* bp = mat + (lane << 4);
    for (uint32_t a = (uint32_t)wave; a + 48 < 1024u; a += 64) {
      const uint4 v0 = *(const uint4*)(bp + ((size_t)a << 10));
      const uint4 v1 = *(const uint4*)(bp + ((size_t)(a + 16) << 10));
      const uint4 v2 = *(const uint4*)(bp + ((size_t)(a + 32) << 10));
      const uint4 v3 = *(const uint4*)(bp + ((size_t)(a + 48) << 10));
      ACC(v0); ACC(v1); ACC(v2); ACC(v3);
    }
    const int basei = (wave << 8) + (lane << 2);
    *(uint4*)&pEa[basei] = make_uint4(aE0, aE1, aE2, aE3);
    *(uint4*)&pOa[basei] = make_uint4(aO0, aO1, aO2, aO3);
  };

  auto gather4 = [&](uint32_t nLv) {        // k4T, 48-B rows, lanes 0..2
    uint32_t aE0=0,aE1=0,aE2=0,aE3=0,aO0=0,aO1=0,aO2=0,aO3=0;
    const uint8_t* bp = k4T + (lane << 4);
    uint32_t a = (uint32_t)wave;
    for (; a + 48 < nLv; a += 64) {
      uint32_t i0 = (uint32_t)__builtin_amdgcn_readfirstlane((int)list[a]);
      uint32_t i1 = (uint32_t)__builtin_amdgcn_readfirstlane((int)list[a + 16]);
      uint32_t i2 = (uint32_t)__builtin_amdgcn_readfirstlane((int)list[a + 32]);
      uint32_t i3 = (uint32_t)__builtin_amdgcn_readfirstlane((int)list[a + 48]);
      const uint4 v0 = *(const uint4*)(bp + (size_t)i0 * 48u);
      const uint4 v1 = *(const uint4*)(bp + (size_t)i1 * 48u);
      const uint4 v2 = *(const uint4*)(bp + (size_t)i2 * 48u);
      const uint4 v3 = *(const uint4*)(bp + (size_t)i3 * 48u);
      ACC(v0); ACC(v1); ACC(v2); ACC(v3);
    }
    for (; a < nLv; a += 16) {
      uint32_t i0 = (uint32_t)__builtin_amdgcn_readfirstlane((int)list[a]);
      const uint4 v0 = *(const uint4*)(bp + (size_t)i0 * 48u);
      ACC(v0);
    }
    const int basei = (wave << 8) + (lane << 2);
    *(uint4*)&pEa[basei] = make_uint4(aE0, aE1, aE2, aE3);
    *(uint4*)&pOa[basei] = make_uint4(aO0, aO1, aO2, aO3);
  };

  auto gather4All = [&]() {
    uint32_t aE0=0,aE1=0,aE2=0,aE3=0,aO0=0,aO1=0,aO2=0,aO3=0;
    const uint8_t* bp = k4T + (lane << 4);
    for (uint32_t a = (uint32_t)wave; a + 48 < 1024u; a += 64) {
      const uint4 v0 = *(const uint4*)(bp + (size_t)a * 48u);
      const uint4 v1 = *(const uint4*)(bp + (size_t)(a + 16) * 48u);
      const uint4 v2 = *(const uint4*)(bp + (size_t)(a + 32) * 48u);
      const uint4 v3 = *(const uint4*)(bp + (size_t)(a + 48) * 48u);
      ACC(v0); ACC(v1); ACC(v2); ACC(v3);
    }
    const int basei = (wave << 8) + (lane << 2);
    *(uint4*)&pEa[basei] = make_uint4(aE0, aE1, aE2, aE3);
    *(uint4*)&pOa[basei] = make_uint4(aO0, aO1, aO2, aO3);
  };

  // packed-u16 sum over 16 groups (fields can't carry: max 15360 < 2^16)
  auto gsum = [&](int jn) -> uint32_t {
    const int w = jn >> 2, sh = (jn & 2) << 3;
    const uint32_t* P = (jn & 1) ? pOa : pEa;
    uint32_t s = 0;
    #pragma unroll
    for (int g = 0; g < 16; ++g) s += P[(g << 8) + w];
    return (s >> sh) & 0xffffu;
  };

  // ---- fused rowsums (replaces k_rowsum) ----
  gatherAll(k2T);
  BARRIER();
  const uint32_t r2v = gsum(tid);
  BARRIER();
  gatherAll(k3T);
  BARRIER();
  const uint32_t r3v = gsum(tid);
  BARRIER();
  if (lane < 3) gather4All();
  BARRIER();
  const uint32_t r4v = (tid < NOUT) ? gsum(tid) : 0u;

  float s1v = out[(size_t)b * NH + tid];    // prefetch spk1 row for t=0

  for (int t = 0; t < NT; ++t) {
    const size_t rowH = ((size_t)t * NB + b) * (size_t)NH;
    const size_t rowO = ((size_t)t * NB + b) * (size_t)NOUT;

    // ---- layer-1 spikes (precomputed by k_spk1); prefetch next row ----
    bool sA = s1v > 0.5f;
    {
      int tn = (t + 1 < NT) ? (t + 1) : t;
      s1v = out[((size_t)tn * NB + b) * (size_t)NH + tid];
    }
    uint64_t b1 = __ballot(sA);
    if (lane == 0) wcnt[wave] = (uint32_t)__popcll(b1);
    BARRIER();                                               // A
    buildList(b1);
    BARRIER();                                               // B
    const uint32_t n1 = nT, nl1 = nL; const bool cm1 = cm;
    if (nl1) gatherBig(k2T, nl1);
    BARRIER();                                               // C

    // ---- layer 2 ----
    bool sp;
    {
      uint32_t gsv = nl1 ? gsum(tid) : 0u;
      uint32_t K = cm1 ? (r2v - gsv) : gsv;
      float cur = fmaf(S2C, (float)K, 0.001f * (float)n1);
      float rst = m2 > 1.0f ? 1.0f : 0.0f;
      m2 = fmaf(0.85f, m2, cur) - rst;
      sp = (m2 - 1.0f) > 0.0f;
      out[O_SPK2 + rowH + tid] = sp ? 1.0f : 0.0f;
    }
    uint64_t b2 = __ballot(sp);
    if (lane == 0) wcnt[wave] = (uint32_t)__popcll(b2);
    BARRIER();                                               // D
    buildList(b2);
    BARRIER();                                               // E
    const uint32_t n2 = nT, nl2 = nL; const bool cm2 = cm;
    if (nl2) gatherBig(k3T, nl2);
    BARRIER();                                               // F

    // ---- layer 3 ----
    {
      uint32_t gsv = nl2 ? gsum(tid) : 0u;
      uint32_t K = cm2 ? (r3v - gsv) : gsv;
      float cur = fmaf(S2C, (float)K, 0.001f * (float)n2);
      float rst = m3 > 1.0f ? 1.0f : 0.0f;
      m3 = fmaf(0.8f, m3, cur) - rst;
      sp = (m3 - 1.0f) > 0.0f;
      out[O_SPK3 + rowH + tid] = sp ? 1.0f : 0.0f;
    }
    uint64_t b3 = __ballot(sp);
    if (lane == 0) wcnt[wave] = (uint32_t)__popcll(b3);
    BARRIER();                                               // G
    buildList(b3);
    BARRIER();                                               // H
    const uint32_t n3 = nT, nl3 = nL; const bool cm3 = cm;

    // ---- layer 4 gather (48-B padded rows; lanes 0..2 of each group) ----
    if (nl3 && lane < 3) gather4(nl3);
    BARRIER();                                               // I

    // ---- layer 4 membrane (reset-to-zero) ----
    if (tid < NOUT) {
      uint32_t gsv = nl3 ? gsum(tid) : 0u;
      uint32_t K = cm3 ? (r4v - gsv) : gsv;
      float cur = fmaf(S2C, (float)K, 0.001f * (float)n3);
      float rst = m4 > 1.0f ? 1.0f : 0.0f;
      float bsv = fmaf(0.95f, m4, cur);
      m4 = (rst > 0.0f) ? 0.0f : bsv;
      out[O_SPK4 + rowO + tid] = ((m4 - 1.0f) > 0.0f) ? 1.0f : 0.0f;
      out[O_MEM4 + rowO + tid] = m4;
    }
  }
}
#undef ACC

extern "C" void kernel_launch(void* const* d_in, const int* in_sizes, int n_in,
                              void* d_out, int out_size, void* d_ws, size_t ws_size,
                              hipStream_t stream)
{
  const float* x  = (const float*)d_in[0];
  const float* w1 = (const float*)d_in[1];
  const float* w2 = (const float*)d_in[2];
  const float* w3 = (const float*)d_in[3];
  const float* w4 = (const float*)d_in[4];
  float* out = (float*)d_out;
  uint8_t* ws = (uint8_t*)d_ws;
  // grid: 512 tile blocks + ceil((49152+131072+3276800)/256)=13504 linear blocks
  hipLaunchKernelGGL(k_prep, dim3(14016), dim3(256), 0, stream, x, w1, w2, w3, w4, ws);
  hipLaunchKernelGGL(k_spk1, dim3(256),  dim3(256), 0, stream,
                     (const float*)(ws + WS_XT), (const float*)(ws + WS_Q1T), out);
  hipLaunchKernelGGL(k_main, dim3(256),  dim3(1024), 0, stream,
                     ws + WS_K2T, ws + WS_K3T, ws + WS_K4T, out);
}

// Round 6
// 693.162 us; speedup vs baseline: 1.2667x; 1.2667x over previous
//
#include <hip/hip_runtime.h>
#include <stdint.h>

// Problem dims
#define NB  256
#define NT  100
#define NIN 128
#define NH  1024
#define NOUT 35

// d_out float offsets
#define O_SPK2 26214400ull
#define O_SPK3 52428800ull
#define O_SPK4 78643200ull
#define O_MEM4 79539200ull

// d_ws byte offsets (R0 layout)
#define WS_XT   0ull          // 25600*128*4 = 13107200
#define WS_Q1T  13107200ull   // 128*1024*4  = 524288
#define WS_K2T  13631488ull   // 1048576
#define WS_K3T  14680064ull   // 1048576
#define WS_K4T  15728640ull   // 1024*48 = 49152 (padded stride 48)

// scale = (w_max - w_min)/15 computed in python fp64 then cast to fp32
#define S2C ((float)((1.0 - 0.001) / 15.0))
#define S1C ((float)(1.0 / 15.0))

// ------------------------------------------------------------------
// K1: quantize weights -> transposed i8 index matrices + q1T fp32 + xt
// (R0 original, proven)
// ------------------------------------------------------------------
__global__ void k_prep(const float* __restrict__ x, const float* __restrict__ w1,
                       const float* __restrict__ w2, const float* __restrict__ w3,
                       const float* __restrict__ w4, uint8_t* __restrict__ ws)
{
  long long id = (long long)blockIdx.x * 256 + threadIdx.x;
  if (id < 1048576) {                       // k2T[i*1024+j] = k(w2[j][i])
    int i = (int)(id >> 10), j = (int)(id & 1023);
    float wv = w2[(size_t)j * 1024 + i];
    float wc = fminf(fmaxf(wv, 0.001f), 1.0f);
    ws[WS_K2T + id] = (uint8_t)(int)rintf((wc - 0.001f) / S2C);
    return;
  }
  id -= 1048576;
  if (id < 1048576) {                       // k3T
    int i = (int)(id >> 10), j = (int)(id & 1023);
    float wv = w3[(size_t)j * 1024 + i];
    float wc = fminf(fmaxf(wv, 0.001f), 1.0f);
    ws[WS_K3T + id] = (uint8_t)(int)rintf((wc - 0.001f) / S2C);
    return;
  }
  id -= 1048576;
  if (id < 49152) {                         // k4T stride 48, pad j>=35 with 0
    int i = (int)(id / 48), j = (int)(id % 48);
    uint8_t v = 0;
    if (j < NOUT) {
      float wv = w4[(size_t)j * 1024 + i];
      float wc = fminf(fmaxf(wv, 0.001f), 1.0f);
      v = (uint8_t)(int)rintf((wc - 0.001f) / S2C);
    }
    ws[WS_K4T + id] = v;
    return;
  }
  id -= 49152;
  if (id < 131072) {                        // q1T[i*1024+j] = fake_quant(w1[j][i]) fp32
    int i = (int)(id >> 10), j = (int)(id & 1023);
    float wv = w1[(size_t)j * 128 + i];
    float wc = fminf(fmaxf(wv, -0.5f), 0.5f);
    float q = rintf((wc + 0.5f) / S1C) * S1C - 0.5f;
    ((float*)(ws + WS_Q1T))[id] = q;
    return;
  }
  id -= 131072;
  if (id < 3276800) {                       // xt[(t*256+b)*128+i] = x[b][t][i]/15
    int row = (int)(id >> 7), i = (int)(id & 127);
    int tt = row >> 8, bb = row & 255;
    ((float*)(ws + WS_XT))[id] = x[((size_t)bb * NT + tt) * NIN + i] / 15.0f;
  }
}

// ------------------------------------------------------------------
// K2: fused layer-1 GEMM + LIF scan, LDS-staged x (R2 v2, proven
// 124 us, absmax 0). 512 threads, neurons j=tid and j=tid+512.
// ------------------------------------------------------------------
__global__ __launch_bounds__(512, 1) void k_spk1(const float* __restrict__ xt,
                                                 const float* __restrict__ q1T,
                                                 float* __restrict__ out)
{
  __shared__ float xs[25 * 128];        // [tt][i], 12.8 KB
  const int b = blockIdx.x;
  const int tid = threadIdx.x;          // 0..511
  float m1a = 0.f, m1b = 0.f;

  for (int c = 0; c < 4; ++c) {
    __syncthreads();                    // xs reuse guard
    {
      int e = tid;                      // first 512 of 800 float4
      int tt = e >> 5, iq = e & 31;
      ((float4*)xs)[e] = *(const float4*)(xt + ((size_t)(c * 25 + tt) * NB + b) * NIN + iq * 4);
      e = tid + 512;
      if (e < 800) {
        tt = e >> 5; iq = e & 31;
        ((float4*)xs)[e] = *(const float4*)(xt + ((size_t)(c * 25 + tt) * NB + b) * NIN + iq * 4);
      }
    }
    __syncthreads();

    float acc0[25], acc1[25];
    #pragma unroll
    for (int tt = 0; tt < 25; ++tt) { acc0[tt] = 0.f; acc1[tt] = 0.f; }

    for (int ib = 0; ib < 16; ++ib) {
      float q0[8], q1v[8];
      #pragma unroll
      for (int u = 0; u < 8; ++u) {
        q0[u]  = q1T[(size_t)(ib * 8 + u) * NH + tid];
        q1v[u] = q1T[(size_t)(ib * 8 + u) * NH + tid + 512];
      }
      #pragma unroll
      for (int tt = 0; tt < 25; ++tt) {
        const float4 xa = *(const float4*)&xs[tt * 128 + ib * 8];
        const float4 xb = *(const float4*)&xs[tt * 128 + ib * 8 + 4];
        acc0[tt] = fmaf(xa.x, q0[0], acc0[tt]);
        acc0[tt] = fmaf(xa.y, q0[1], acc0[tt]);
        acc0[tt] = fmaf(xa.z, q0[2], acc0[tt]);
        acc0[tt] = fmaf(xa.w, q0[3], acc0[tt]);
        acc0[tt] = fmaf(xb.x, q0[4], acc0[tt]);
        acc0[tt] = fmaf(xb.y, q0[5], acc0[tt]);
        acc0[tt] = fmaf(xb.z, q0[6], acc0[tt]);
        acc0[tt] = fmaf(xb.w, q0[7], acc0[tt]);
        acc1[tt] = fmaf(xa.x, q1v[0], acc1[tt]);
        acc1[tt] = fmaf(xa.y, q1v[1], acc1[tt]);
        acc1[tt] = fmaf(xa.z, q1v[2], acc1[tt]);
        acc1[tt] = fmaf(xa.w, q1v[3], acc1[tt]);
        acc1[tt] = fmaf(xb.x, q1v[4], acc1[tt]);
        acc1[tt] = fmaf(xb.y, q1v[5], acc1[tt]);
        acc1[tt] = fmaf(xb.z, q1v[6], acc1[tt]);
        acc1[tt] = fmaf(xb.w, q1v[7], acc1[tt]);
      }
    }
    #pragma unroll
    for (int tt = 0; tt < 25; ++tt) {   // sequential LIF scan (subtract-reset)
      const int t = c * 25 + tt;
      const size_t row = ((size_t)t * NB + b) * (size_t)NH;
      float rst0 = m1a > 1.0f ? 1.0f : 0.0f;
      m1a = fmaf(0.9f, m1a, acc0[tt]) - rst0;
      out[row + tid] = ((m1a - 1.0f) > 0.0f) ? 1.0f : 0.0f;
      float rst1 = m1b > 1.0f ? 1.0f : 0.0f;
      m1b = fmaf(0.9f, m1b, acc1[tt]) - rst1;
      out[row + tid + 512] = ((m1b - 1.0f) > 0.0f) ? 1.0f : 0.0f;
    }
  }
}

// ------------------------------------------------------------------
// K3: persistent per-batch-element SNN loop. R0's proven 512-thread
// structure (8 waves, 2 neurons/thread) with: layer-1 = spike reads,
// atomic-free list build, depth-4 gathers, fused rowsums.
// ------------------------------------------------------------------
#define ACC(V) do { \
  aE0 += (V).x & 0x00FF00FFu; aO0 += ((V).x >> 8) & 0x00FF00FFu; \
  aE1 += (V).y & 0x00FF00FFu; aO1 += ((V).y >> 8) & 0x00FF00FFu; \
  aE2 += (V).z & 0x00FF00FFu; aO2 += ((V).z >> 8) & 0x00FF00FFu; \
  aE3 += (V).w & 0x00FF00FFu; aO3 += ((V).w >> 8) & 0x00FF00FFu; } while (0)

__global__ __launch_bounds__(512, 1) void k_main(
    const uint8_t* __restrict__ k2T, const uint8_t* __restrict__ k3T,
    const uint8_t* __restrict__ k4T, float* __restrict__ out)
{
  const int b = blockIdx.x;
  const int tid = threadIdx.x;
  const int lane = tid & 63;
  const int wave = tid >> 6;            // 8 gather groups

  __shared__ uint16_t list[1024];
  __shared__ uint4    pEa4[512];        // [g<8][lane*4..+3] packed u16 sums
  __shared__ uint4    pOa4[512];
  __shared__ uint4    wcnt4[2];
  uint32_t* pEa  = (uint32_t*)pEa4;
  uint32_t* pOa  = (uint32_t*)pOa4;
  uint32_t* wcnt = (uint32_t*)wcnt4;

  float m2[2] = {0.f, 0.f}, m3[2] = {0.f, 0.f}, m4 = 0.f;
  uint32_t nT, nL; bool cm;

  // atomic-free list build: register prefix over per-wave counts
  auto buildList = [&](uint64_t bA, uint64_t bB) {   // wcnt[wave] already written, post-barrier
    const uint4 c0 = wcnt4[0], c1 = wcnt4[1];
    nT = c0.x + c0.y + c0.z + c0.w + c1.x + c1.y + c1.z + c1.w;
    cm = nT > 512;
    nL = cm ? (1024u - nT) : nT;
    uint32_t pre = 0;
    pre += (wave > 0) ? c0.x : 0u;  pre += (wave > 1) ? c0.y : 0u;
    pre += (wave > 2) ? c0.z : 0u;  pre += (wave > 3) ? c0.w : 0u;
    pre += (wave > 4) ? c1.x : 0u;  pre += (wave > 5) ? c1.y : 0u;
    pre += (wave > 6) ? c1.z : 0u;
    const uint32_t bs = cm ? ((uint32_t)(wave << 7) - pre) : pre;
    const uint64_t cA = cm ? ~bA : bA;
    const uint64_t cB = cm ? ~bB : bB;
    const uint64_t ltm = (1ull << lane) - 1ull;
    if ((cA >> lane) & 1ull)
      list[bs + (uint32_t)__popcll(cA & ltm)] = (uint16_t)tid;
    if ((cB >> lane) & 1ull)
      list[bs + (uint32_t)__popcll(cA) + (uint32_t)__popcll(cB & ltm)] = (uint16_t)(tid + 512);
  };

  auto gatherBig = [&](const uint8_t* __restrict__ mat, uint32_t nLv) {
    uint32_t aE0=0,aE1=0,aE2=0,aE3=0,aO0=0,aO1=0,aO2=0,aO3=0;
    const uint8_t* bp = mat + (lane << 4);   // 64 lanes x 16B = full 1KB row
    uint32_t a = (uint32_t)wave;
    for (; a + 24 < nLv; a += 32) {          // 4 loads in flight
      uint32_t i0 = (uint32_t)__builtin_amdgcn_readfirstlane((int)list[a]);
      uint32_t i1 = (uint32_t)__builtin_amdgcn_readfirstlane((int)list[a + 8]);
      uint32_t i2 = (uint32_t)__builtin_amdgcn_readfirstlane((int)list[a + 16]);
      uint32_t i3 = (uint32_t)__builtin_amdgcn_readfirstlane((int)list[a + 24]);
      const uint4 v0 = *(const uint4*)(bp + ((size_t)i0 << 10));
      const uint4 v1 = *(const uint4*)(bp + ((size_t)i1 << 10));
      const uint4 v2 = *(const uint4*)(bp + ((size_t)i2 << 10));
      const uint4 v3 = *(const uint4*)(bp + ((size_t)i3 << 10));
      ACC(v0); ACC(v1); ACC(v2); ACC(v3);
    }
    for (; a < nLv; a += 8) {
      uint32_t i0 = (uint32_t)__builtin_amdgcn_readfirstlane((int)list[a]);
      const uint4 v0 = *(const uint4*)(bp + ((size_t)i0 << 10));
      ACC(v0);
    }
    const int basei = (wave << 8) + (lane << 2);
    *(uint4*)&pEa[basei] = make_uint4(aE0, aE1, aE2, aE3);
    *(uint4*)&pOa[basei] = make_uint4(aO0, aO1, aO2, aO3);
  };

  auto gatherAll = [&](const uint8_t* __restrict__ mat) {   // all 1024 rows
    uint32_t aE0=0,aE1=0,aE2=0,aE3=0,aO0=0,aO1=0,aO2=0,aO3=0;
    const uint8_t* bp = mat + (lane << 4);
    for (uint32_t a = (uint32_t)wave; a + 24 < 1024u; a += 32) {
      const uint4 v0 = *(const uint4*)(bp + ((size_t)a << 10));
      const uint4 v1 = *(const uint4*)(bp + ((size_t)(a + 8) << 10));
      const uint4 v2 = *(const uint4*)(bp + ((size_t)(a + 16) << 10));
      const uint4 v3 = *(const uint4*)(bp + ((size_t)(a + 24) << 10));
      ACC(v0); ACC(v1); ACC(v2); ACC(v3);
    }
    const int basei = (wave << 8) + (lane << 2);
    *(uint4*)&pEa[basei] = make_uint4(aE0, aE1, aE2, aE3);
    *(uint4*)&pOa[basei] = make_uint4(aO0, aO1, aO2, aO3);
  };

  auto gather4 = [&](uint32_t nLv) {         // k4T, 48-B rows, lanes 0..2
    uint32_t aE0=0,aE1=0,aE2=0,aE3=0,aO0=0,aO1=0,aO2=0,aO3=0;
    const uint8_t* bp = k4T + (lane << 4);
    uint32_t a = (uint32_t)wave;
    for (; a + 24 < nLv; a += 32) {
      uint32_t i0 = (uint32_t)__builtin_amdgcn_readfirstlane((int)list[a]);
      uint32_t i1 = (uint32_t)__builtin_amdgcn_readfirstlane((int)list[a + 8]);
      uint32_t i2 = (uint32_t)__builtin_amdgcn_readfirstlane((int)list[a + 16]);
      uint32_t i3 = (uint32_t)__builtin_amdgcn_readfirstlane((int)list[a + 24]);
      const uint4 v0 = *(const uint4*)(bp + (size_t)i0 * 48u);
      const uint4 v1 = *(const uint4*)(bp + (size_t)i1 * 48u);
      const uint4 v2 = *(const uint4*)(bp + (size_t)i2 * 48u);
      const uint4 v3 = *(const uint4*)(bp + (size_t)i3 * 48u);
      ACC(v0); ACC(v1); ACC(v2); ACC(v3);
    }
    for (; a < nLv; a += 8) {
      uint32_t i0 = (uint32_t)__builtin_amdgcn_readfirstlane((int)list[a]);
      const uint4 v0 = *(const uint4*)(bp + (size_t)i0 * 48u);
      ACC(v0);
    }
    const int basei = (wave << 8) + (lane << 2);
    *(uint4*)&pEa[basei] = make_uint4(aE0, aE1, aE2, aE3);
    *(uint4*)&pOa[basei] = make_uint4(aO0, aO1, aO2, aO3);
  };

  auto gather4All = [&]() {
    uint32_t aE0=0,aE1=0,aE2=0,aE3=0,aO0=0,aO1=0,aO2=0,aO3=0;
    const uint8_t* bp = k4T + (lane << 4);
    for (uint32_t a = (uint32_t)wave; a + 24 < 1024u; a += 32) {
      const uint4 v0 = *(const uint4*)(bp + (size_t)a * 48u);
      const uint4 v1 = *(const uint4*)(bp + (size_t)(a + 8) * 48u);
      const uint4 v2 = *(const uint4*)(bp + (size_t)(a + 16) * 48u);
      const uint4 v3 = *(const uint4*)(bp + (size_t)(a + 24) * 48u);
      ACC(v0); ACC(v1); ACC(v2); ACC(v3);
    }
    const int basei = (wave << 8) + (lane << 2);
    *(uint4*)&pEa[basei] = make_uint4(aE0, aE1, aE2, aE3);
    *(uint4*)&pOa[basei] = make_uint4(aO0, aO1, aO2, aO3);
  };

  // packed-u16 sum over 8 groups (fields can't carry: max 15360 < 2^16)
  auto gsum = [&](int jn) -> uint32_t {
    const int w = jn >> 2, sh = (jn & 2) << 3;
    const uint32_t* P = (jn & 1) ? pOa : pEa;
    uint32_t s = 0;
    #pragma unroll
    for (int g = 0; g < 8; ++g) s += P[(g << 8) + w];
    return (s >> sh) & 0xffffu;
  };

  // ---- fused rowsums (replaces k_rowsum) ----
  gatherAll(k2T);
  __syncthreads();
  uint32_t r2[2]; r2[0] = gsum(tid); r2[1] = gsum(tid + 512);
  __syncthreads();
  gatherAll(k3T);
  __syncthreads();
  uint32_t r3[2]; r3[0] = gsum(tid); r3[1] = gsum(tid + 512);
  __syncthreads();
  if (lane < 3) gather4All();
  __syncthreads();
  const uint32_t r4v = (tid < NOUT) ? gsum(tid) : 0u;

  // prefetch spk1 row for t=0
  float s1a = out[(size_t)b * NH + tid];
  float s1b = out[(size_t)b * NH + tid + 512];

  for (int t = 0; t < NT; ++t) {
    const size_t rowH = ((size_t)t * NB + b) * (size_t)NH;
    const size_t rowO = ((size_t)t * NB + b) * (size_t)NOUT;

    // ---- layer-1 spikes (precomputed by k_spk1); prefetch next row ----
    bool sA = s1a > 0.5f, sB = s1b > 0.5f;
    {
      int tn = (t + 1 < NT) ? (t + 1) : t;
      size_t rowN = ((size_t)tn * NB + b) * (size_t)NH;
      s1a = out[rowN + tid];
      s1b = out[rowN + tid + 512];
    }
    uint64_t bA = __ballot(sA), bB = __ballot(sB);
    if (lane == 0) wcnt[wave] = (uint32_t)(__popcll(bA) + __popcll(bB));
    __syncthreads();                                         // A
    buildList(bA, bB);
    __syncthreads();                                         // B
    const uint32_t n1 = nT, nl1 = nL; const bool cm1 = cm;
    if (nl1) gatherBig(k2T, nl1);
    __syncthreads();                                         // C

    // ---- layer 2 ----
    {
      float nb = 0.001f * (float)n1;
      #pragma unroll
      for (int c = 0; c < 2; ++c) {
        int j = (c << 9) + tid;
        uint32_t gsv = nl1 ? gsum(j) : 0u;
        uint32_t K = cm1 ? (r2[c] - gsv) : gsv;
        float cur = fmaf(S2C, (float)K, nb);
        float rst = m2[c] > 1.0f ? 1.0f : 0.0f;
        m2[c] = fmaf(0.85f, m2[c], cur) - rst;
        bool sp = (m2[c] - 1.0f) > 0.0f;
        out[O_SPK2 + rowH + j] = sp ? 1.0f : 0.0f;
        if (c == 0) sA = sp; else sB = sp;
      }
    }
    bA = __ballot(sA); bB = __ballot(sB);
    if (lane == 0) wcnt[wave] = (uint32_t)(__popcll(bA) + __popcll(bB));
    __syncthreads();                                         // D
    buildList(bA, bB);
    __syncthreads();                                         // E
    const uint32_t n2 = nT, nl2 = nL; const bool cm2 = cm;
    if (nl2) gatherBig(k3T, nl2);
    __syncthreads();                                         // F

    // ---- layer 3 ----
    {
      float nb = 0.001f * (float)n2;
      #pragma unroll
      for (int c = 0; c < 2; ++c) {
        int j = (c << 9) + tid;
        uint32_t gsv = nl2 ? gsum(j) : 0u;
        uint32_t K = cm2 ? (r3[c] - gsv) : gsv;
        float cur = fmaf(S2C, (float)K, nb);
        float rst = m3[c] > 1.0f ? 1.0f : 0.0f;
        m3[c] = fmaf(0.8f, m3[c], cur) - rst;
        bool sp = (m3[c] - 1.0f) > 0.0f;
        out[O_SPK3 + rowH + j] = sp ? 1.0f : 0.0f;
        if (c == 0) sA = sp; else sB = sp;
      }
    }
    bA = __ballot(sA); bB = __ballot(sB);
    if (lane == 0) wcnt[wave] = (uint32_t)(__popcll(bA) + __popcll(bB));
    __syncthreads();                                         // G
    buildList(bA, bB);
    __syncthreads();                                         // H
    const uint32_t n3 = nT, nl3 = nL; const bool cm3 = cm;

    // ---- layer 4 gather (48-B padded rows; lanes 0..2 of each group) ----
    if (nl3 && lane < 3) gather4(nl3);
    __syncthreads();                                         // I

    // ---- layer 4 membrane (reset-to-zero) ----
    if (tid < NOUT) {
      uint32_t gsv = nl3 ? gsum(tid) : 0u;
      uint32_t K = cm3 ? (r4v - gsv) : gsv;
      float cur = fmaf(S2C, (float)K, 0.001f * (float)n3);
      float rst = m4 > 1.0f ? 1.0f : 0.0f;
      float bsv = fmaf(0.95f, m4, cur);
      m4 = (rst > 0.0f) ? 0.0f : bsv;
      out[O_SPK4 + rowO + tid] = ((m4 - 1.0f) > 0.0f) ? 1.0f : 0.0f;
      out[O_MEM4 + rowO + tid] = m4;
    }
  }
}
#undef ACC

extern "C" void kernel_launch(void* const* d_in, const int* in_sizes, int n_in,
                              void* d_out, int out_size, void* d_ws, size_t ws_size,
                              hipStream_t stream)
{
  const float* x  = (const float*)d_in[0];
  const float* w1 = (const float*)d_in[1];
  const float* w2 = (const float*)d_in[2];
  const float* w3 = (const float*)d_in[3];
  const float* w4 = (const float*)d_in[4];
  float* out = (float*)d_out;
  uint8_t* ws = (uint8_t*)d_ws;
  hipLaunchKernelGGL(k_prep, dim3(21696), dim3(256), 0, stream, x, w1, w2, w3, w4, ws);
  hipLaunchKernelGGL(k_spk1, dim3(256),   dim3(512), 0, stream,
                     (const float*)(ws + WS_XT), (const float*)(ws + WS_Q1T), out);
  hipLaunchKernelGGL(k_main, dim3(256),   dim3(512), 0, stream,
                     ws + WS_K2T, ws + WS_K3T, ws + WS_K4T, out);
}